// Round 13
// baseline (389.978 us; speedup 1.0000x reference)
//
#include <hip/hip_runtime.h>

#define NN 100000
#define DD 256
#define SCAN_BLK 1024

typedef unsigned int uint;
typedef unsigned short ushort;
typedef __attribute__((ext_vector_type(8))) short bfx8;
typedef __attribute__((ext_vector_type(4))) float fx4;

__device__ __forceinline__ ushort f2bf(float f) {  // RNE
    uint u = __float_as_uint(f);
    u += 0x7fff + ((u >> 16) & 1);
    return (ushort)(u >> 16);
}

__device__ __forceinline__ uint cvtpk(float lo, float hi) {  // 2xf32 -> packed bf16
    uint r;
    asm("v_cvt_pk_bf16_f32 %0, %1, %2" : "=v"(r) : "v"(lo), "v"(hi));
    return r;
}

// ---------------- degree count (deg arrays memset to 0 host-side) ----------
__global__ __launch_bounds__(256) void k_count(const int* __restrict__ src,
                                               const int* __restrict__ dst, int E,
                                               int* __restrict__ dego,
                                               int* __restrict__ degi) {
    int e = blockIdx.x * 256 + threadIdx.x;
    if (e < E) {
        atomicAdd(&dego[src[e]], 1);
        atomicAdd(&degi[dst[e]], 1);
    }
}

// ---------------- CSR build (scan by dst; degi = real in-edges) -------------
__device__ __forceinline__ int block_scan_inc(int v, int* sm) {
    int t = threadIdx.x;
    sm[t] = v;
    __syncthreads();
    for (int o = 1; o < SCAN_BLK; o <<= 1) {
        int x = (t >= o) ? sm[t - o] : 0;
        __syncthreads();
        sm[t] += x;
        __syncthreads();
    }
    return sm[t];
}

// scan1 fused with norm computation
__global__ __launch_bounds__(SCAN_BLK) void k_scan1n(const int* __restrict__ degi,
                                                     const int* __restrict__ dego,
                                                     int* __restrict__ partials,
                                                     float* __restrict__ ns,
                                                     float* __restrict__ nd) {
    __shared__ int sm[SCAN_BLK];
    int i = blockIdx.x * SCAN_BLK + threadIdx.x;
    int v = (i < NN) ? degi[i] : 0;
    if (i < NN) {
        ns[i] = rsqrtf((float)(dego[i] + 1));  // +1 = self-loop
        nd[i] = rsqrtf((float)(v + 1));
    }
    block_scan_inc(v, sm);
    if (threadIdx.x == 0) partials[blockIdx.x] = sm[SCAN_BLK - 1];
}

// scan2 fused with the W -> fragment-order Wf permutation (block 0 scans,
// blocks 1..64 convert). Wf: frag (c16,kf) = cols c16*16..+15, k kf*32..+31;
// lane l owns col c16*16+(l&15), k kf*32+(l>>4)*8..+7, at Wf[((c16*8+kf)*64+l)*8].
// A wave's bfx8 B-load is 64 lanes x 16 B CONTIGUOUS (1 KB burst).
__global__ __launch_bounds__(256) void k_scan2cw(int* __restrict__ partials, int nb,
                                                 const float* __restrict__ W1,
                                                 const float* __restrict__ W2,
                                                 ushort* __restrict__ Wf1,
                                                 ushort* __restrict__ Wf2) {
    if (blockIdx.x == 0) {
        __shared__ int sm[128];
        int t = threadIdx.x;
        int v = (t < 128 && t < nb) ? partials[t] : 0;
        if (t < 128) sm[t] = v;
        __syncthreads();
        for (int o = 1; o < 128; o <<= 1) {
            int x = (t < 128 && t >= o) ? sm[t - o] : 0;
            __syncthreads();
            if (t < 128) sm[t] += x;
            __syncthreads();
        }
        if (t < nb) partials[t] = sm[t] - v;  // exclusive
    } else {
        int tid = (blockIdx.x - 1) * 256 + threadIdx.x;  // 0..16383
        int m = tid >> 13;
        int r = tid & 8191;
        int lane = r & 63;
        int kf = (r >> 6) & 7;
        int c16 = r >> 9;
        int n = c16 * 16 + (lane & 15);
        int kb = kf * 32 + (lane >> 4) * 8;
        const float* W = m ? W2 : W1;
        ushort* Wf = m ? Wf2 : Wf1;
        uint4 u;
        u.x = (uint)f2bf(W[(size_t)(kb + 0) * DD + n]) |
              ((uint)f2bf(W[(size_t)(kb + 1) * DD + n]) << 16);
        u.y = (uint)f2bf(W[(size_t)(kb + 2) * DD + n]) |
              ((uint)f2bf(W[(size_t)(kb + 3) * DD + n]) << 16);
        u.z = (uint)f2bf(W[(size_t)(kb + 4) * DD + n]) |
              ((uint)f2bf(W[(size_t)(kb + 5) * DD + n]) << 16);
        u.w = (uint)f2bf(W[(size_t)(kb + 6) * DD + n]) |
              ((uint)f2bf(W[(size_t)(kb + 7) * DD + n]) << 16);
        *(uint4*)&Wf[(size_t)r * 8] = u;
    }
}

__global__ __launch_bounds__(SCAN_BLK) void k_scan3(const int* __restrict__ degi,
                                                    const int* __restrict__ partials,
                                                    int* __restrict__ rowptr,
                                                    int* __restrict__ cursor) {
    __shared__ int sm[SCAN_BLK];
    int i = blockIdx.x * SCAN_BLK + threadIdx.x;
    int v = (i < NN) ? degi[i] : 0;
    int incl = block_scan_inc(v, sm);
    int excl = partials[blockIdx.x] + incl - v;
    if (i <= NN) rowptr[i] = excl;   // rowptr[NN] = E
    if (i < NN) cursor[i] = excl;
}

__global__ __launch_bounds__(256) void k_fill(const int* __restrict__ src,
                                              const int* __restrict__ dst, int E,
                                              int* __restrict__ cursor,
                                              int* __restrict__ eidx) {
    int e = blockIdx.x * 256 + threadIdx.x;
    if (e < E) {
        int d = dst[e];
        int p = atomicAdd(&cursor[d], 1);
        eidx[p] = src[e];
    }
}

// ---------------- MFMA GEMM: H = A @ W (optionally row-scaled) -------------
// WHOLE-TILE staging: the entire 128x256 bf16 A-tile (64 KB) is staged into
// LDS up front, then ONE barrier, then the full 128-MFMA K-loop runs with
// ZERO barriers. Round-12 had 4 K-step barriers, each forcing a
// s_waitcnt vmcnt(0) drain of the "async" global_load_lds prefetch (the m97
// drain) — staging latency was serialized 4x per block. Now it is paid once,
// and hides under the other resident block (2 blocks/CU, launch_bounds cap).
//   FP32A:  4 ping-pong reg bursts (named sva/svb arrays — no runtime idx),
//           cvt_pk to bf16, swizzled ds_write. Row-scale nrm in epilogue.
//   !FP32A: 8 global_load_lds calls/thread (pre-swizzled source, linear dest).
// B from fragment-order Wf (L2-resident, 1 KB coalesced bursts per frag).
// Epilogue: full 128x256 LDS tile (reuses atq), coalesced uint4 stores.
template <bool FP32A>
__global__ __launch_bounds__(512, 4) void k_mfgemm(const void* __restrict__ Av,
                                                   const float* __restrict__ nrm,
                                                   const ushort* __restrict__ Wf,
                                                   ushort* __restrict__ H) {
    __shared__ uint4 atq[4096];  // whole A-tile as bf16: [ks][128 r][8 chunks]
    int t = threadIdx.x;
    int brow = blockIdx.x * 128;
    int lane = t & 63, w = t >> 6;
    int wr = w >> 2, wc = w & 3;       // wave grid 2x4
    int lg = lane >> 4, lr = lane & 15;

    // ---- stage the whole tile ----
    if (FP32A) {
        const float* X = (const float*)Av;
        float4 sva[2][2], svb[2][2];
        auto ldF = [&](int b, float4 (*sv)[2]) {
#pragma unroll
            for (int s = 0; s < 2; ++s) {
                int slot = (b * 2 + s) * 512 + t;
                int ks = slot >> 10, r = (slot & 1023) >> 3;
                int cc = (slot & 7) ^ (r & 7);   // inverse swizzle on source
                int row = brow + r;
                if (row >= NN) row = NN - 1;     // tail clamp (stores masked)
                const float4* p4 =
                    (const float4*)(X + (size_t)row * DD + ks * 64 + cc * 8);
                sv[s][0] = p4[0];
                sv[s][1] = p4[1];
            }
        };
        auto wrF = [&](int b, const float4 (*sv)[2]) {
#pragma unroll
            for (int s = 0; s < 2; ++s) {
                int slot = (b * 2 + s) * 512 + t;
                uint4 u;
                u.x = cvtpk(sv[s][0].x, sv[s][0].y);
                u.y = cvtpk(sv[s][0].z, sv[s][0].w);
                u.z = cvtpk(sv[s][1].x, sv[s][1].y);
                u.w = cvtpk(sv[s][1].z, sv[s][1].w);
                atq[slot] = u;
            }
        };
        ldF(0, sva);
        ldF(1, svb);
        wrF(0, sva);
        ldF(2, sva);
        wrF(1, svb);
        ldF(3, svb);
        wrF(2, sva);
        wrF(3, svb);
    } else {
#pragma unroll
        for (int i = 0; i < 8; ++i) {
            int slot = i * 512 + w * 64 + lane;  // this lane's dest slot
            int ks = slot >> 10, r = (slot & 1023) >> 3;
            int cs = (slot & 7) ^ (r & 7);       // inverse swizzle on source
            int row = brow + r;
            if (row >= NN) row = NN - 1;
            const ushort* g = (const ushort*)Av + (size_t)row * DD + ks * 64 + cs * 8;
            __builtin_amdgcn_global_load_lds(
                (const __attribute__((address_space(1))) uint*)g,
                (__attribute__((address_space(3))) uint*)&atq[i * 512 + w * 64],
                16, 0, 0);
        }
    }

    // ---- B: fragment-order, coalesced 1 KB bursts ----
    bfx8 bfr2[2][4];
    auto ldB = [&](int ks) {
#pragma unroll
        for (int kk = 0; kk < 2; ++kk)
#pragma unroll
            for (int ni = 0; ni < 4; ++ni)
                bfr2[kk][ni] = *(const bfx8*)&Wf[
                    (((size_t)(wc * 4 + ni) * 8 + (ks * 2 + kk)) * 64 + lane) * 8];
    };
    ldB(0);

    fx4 acc[4][4];
#pragma unroll
    for (int mi = 0; mi < 4; ++mi)
#pragma unroll
        for (int ni = 0; ni < 4; ++ni)
            acc[mi][ni] = (fx4){0.f, 0.f, 0.f, 0.f};

    __syncthreads();  // the ONE staging drain: whole tile + B(0) landed

    // ---- barrier-free K-loop: 128 MFMAs ----
#pragma unroll
    for (int ks = 0; ks < 4; ++ks) {
#pragma unroll
        for (int kk = 0; kk < 2; ++kk)
#pragma unroll
            for (int mi = 0; mi < 4; ++mi) {
                int r = wr * 64 + mi * 16 + lr;
                int c = kk * 4 + lg;
                bfx8 af = *(const bfx8*)&atq[ks * 1024 + r * 8 + (c ^ (r & 7))];
#pragma unroll
                for (int ni = 0; ni < 4; ++ni)
                    acc[mi][ni] = __builtin_amdgcn_mfma_f32_16x16x32_bf16(
                        af, bfr2[kk][ni], acc[mi][ni], 0, 0, 0);
            }
        if (ks < 3) ldB(ks + 1);  // after last consumer of bfr2
    }

    __syncthreads();  // all LDS tile reads complete; atq reusable

    // ---- epilogue: full 128x256 tile via LDS, coalesced stores ----
    float scl[4][4];
    if (FP32A) {
#pragma unroll
        for (int mi = 0; mi < 4; ++mi)
#pragma unroll
            for (int j = 0; j < 4; ++j) {
                int row = brow + wr * 64 + mi * 16 + lg * 4 + j;
                scl[mi][j] = nrm[row < NN ? row : NN - 1];
            }
    }
    ushort* hs = (ushort*)atq;  // 128 rows x 256 ushorts = 64 KB
#pragma unroll
    for (int mi = 0; mi < 4; ++mi)
#pragma unroll
        for (int ni = 0; ni < 4; ++ni)
#pragma unroll
            for (int j = 0; j < 4; ++j) {
                int r = wr * 64 + mi * 16 + lg * 4 + j;  // 0..127
                int c = wc * 64 + ni * 16 + lr;
                float v = acc[mi][ni][j];
                if (FP32A) v *= scl[mi][j];
                hs[r * 256 + (((c >> 3) ^ (r & 7)) << 3) + (c & 7)] = f2bf(v);
            }
    __syncthreads();
    {
        int rl = t >> 2;               // 0..127, 4 threads/row
        int grow = brow + rl;
        if (grow < NN) {
            ushort* hp = H + (size_t)grow * DD;
#pragma unroll
            for (int i = 0; i < 8; ++i) {
                int ch = (t & 3) * 8 + i;
                uint4 v = *(const uint4*)&hs[rl * 256 + ((ch ^ (rl & 7)) << 3)];
                *(uint4*)(hp + ch * 8) = v;
            }
        }
    }
}

// ---------------- SpMM (bf16 gather, fp32 accum): one wave per dst node ----
__global__ __launch_bounds__(256) void k_spmm_bf(const ushort* __restrict__ T,
                                                 const int* __restrict__ rowptr,
                                                 const int* __restrict__ eidx,
                                                 const float* __restrict__ nd,
                                                 const float* __restrict__ ns,
                                                 const float* __restrict__ bias,
                                                 ushort* __restrict__ obf,
                                                 float* __restrict__ of,
                                                 int layer1) {
    int wid = threadIdx.x >> 6, lane = threadIdx.x & 63;
    int node = blockIdx.x * 4 + wid;
    if (node >= NN) return;
    int c = lane << 2;  // 4 bf16 per lane
    uint2 sv = *(const uint2*)(T + (size_t)node * DD + c);  // self-loop
    float p0[4], p1[4], p2[4], p3[4];
    p0[0] = __uint_as_float(sv.x << 16);
    p0[1] = __uint_as_float(sv.x & 0xffff0000u);
    p0[2] = __uint_as_float(sv.y << 16);
    p0[3] = __uint_as_float(sv.y & 0xffff0000u);
#pragma unroll
    for (int j = 0; j < 4; ++j) { p1[j] = 0.f; p2[j] = 0.f; p3[j] = 0.f; }
    int e = rowptr[node], end = rowptr[node + 1];
    for (; e + 3 < end; e += 4) {
        int s0 = eidx[e], s1 = eidx[e + 1], s2 = eidx[e + 2], s3 = eidx[e + 3];
        uint2 v0 = *(const uint2*)(T + (size_t)s0 * DD + c);
        uint2 v1 = *(const uint2*)(T + (size_t)s1 * DD + c);
        uint2 v2 = *(const uint2*)(T + (size_t)s2 * DD + c);
        uint2 v3 = *(const uint2*)(T + (size_t)s3 * DD + c);
        p0[0] += __uint_as_float(v0.x << 16);
        p0[1] += __uint_as_float(v0.x & 0xffff0000u);
        p0[2] += __uint_as_float(v0.y << 16);
        p0[3] += __uint_as_float(v0.y & 0xffff0000u);
        p1[0] += __uint_as_float(v1.x << 16);
        p1[1] += __uint_as_float(v1.x & 0xffff0000u);
        p1[2] += __uint_as_float(v1.y << 16);
        p1[3] += __uint_as_float(v1.y & 0xffff0000u);
        p2[0] += __uint_as_float(v2.x << 16);
        p2[1] += __uint_as_float(v2.x & 0xffff0000u);
        p2[2] += __uint_as_float(v2.y << 16);
        p2[3] += __uint_as_float(v2.y & 0xffff0000u);
        p3[0] += __uint_as_float(v3.x << 16);
        p3[1] += __uint_as_float(v3.x & 0xffff0000u);
        p3[2] += __uint_as_float(v3.y << 16);
        p3[3] += __uint_as_float(v3.y & 0xffff0000u);
    }
    for (; e < end; ++e) {
        int s0 = eidx[e];
        uint2 v0 = *(const uint2*)(T + (size_t)s0 * DD + c);
        p0[0] += __uint_as_float(v0.x << 16);
        p0[1] += __uint_as_float(v0.x & 0xffff0000u);
        p0[2] += __uint_as_float(v0.y << 16);
        p0[3] += __uint_as_float(v0.y & 0xffff0000u);
    }
#pragma unroll
    for (int j = 0; j < 4; ++j) p0[j] += (p1[j] + p2[j]) + p3[j];
    float n = nd[node];
    float4 bb = *(const float4*)(bias + c);
    float o0 = fmaf(p0[0], n, bb.x);
    float o1 = fmaf(p0[1], n, bb.y);
    float o2 = fmaf(p0[2], n, bb.z);
    float o3 = fmaf(p0[3], n, bb.w);
    if (layer1) {
        float s = ns[node];
        o0 = fmaxf(o0, 0.f) * s; o1 = fmaxf(o1, 0.f) * s;
        o2 = fmaxf(o2, 0.f) * s; o3 = fmaxf(o3, 0.f) * s;
        uint lo = (uint)f2bf(o0) | ((uint)f2bf(o1) << 16);
        uint hi = (uint)f2bf(o2) | ((uint)f2bf(o3) << 16);
        *(uint2*)(obf + (size_t)node * DD + c) = make_uint2(lo, hi);
    } else {
        fx4 o = {o0, o1, o2, o3};
        __builtin_nontemporal_store(o, (fx4*)(of + (size_t)node * DD + c));
    }
}

extern "C" void kernel_launch(void* const* d_in, const int* in_sizes, int n_in,
                              void* d_out, int out_size, void* d_ws, size_t ws_size,
                              hipStream_t stream) {
    const float* features = (const float*)d_in[0];
    const int* src = (const int*)d_in[1];
    const int* dst = (const int*)d_in[2];
    const float* W1 = (const float*)d_in[3];
    const float* b1 = (const float*)d_in[4];
    const float* W2 = (const float*)d_in[5];
    const float* b2 = (const float*)d_in[6];
    int E = in_sizes[1];
    float* out = (float*)d_out;

    size_t off = 0;
    auto alloc = [&](size_t nbytes) -> void* {
        void* p = (char*)d_ws + off;
        off += (nbytes + 255) & ~(size_t)255;
        return p;
    };
    int* dego = (int*)alloc((size_t)NN * 4);      // offset 0
    int* degi = (int*)alloc((size_t)NN * 4);      // offset 400128 (contiguous)
    float* norm_src = (float*)alloc((size_t)NN * 4);
    float* norm_dst = (float*)alloc((size_t)NN * 4);
    int* rowptr = (int*)alloc((size_t)(NN + 1) * 4);
    int* cursor = (int*)alloc((size_t)NN * 4);
    int* partials = (int*)alloc(128 * 4);
    int* eidx = (int*)alloc((size_t)E * 4);
    ushort* Wf1 = (ushort*)alloc((size_t)DD * DD * 2);
    ushort* Wf2 = (ushort*)alloc((size_t)DD * DD * 2);
    ushort* Xbf = (ushort*)alloc((size_t)NN * DD * 2);
    ushort* Hbf = (ushort*)alloc((size_t)NN * DD * 2);

    const int NB = (NN + SCAN_BLK - 1) / SCAN_BLK;  // 98

    hipMemsetAsync(dego, 0, (size_t)2 * 400128, stream);  // dego+degi adjacent
    k_count<<<(E + 255) / 256, 256, 0, stream>>>(src, dst, E, dego, degi);
    k_scan1n<<<NB, SCAN_BLK, 0, stream>>>(degi, dego, partials, norm_src, norm_dst);
    k_scan2cw<<<65, 256, 0, stream>>>(partials, NB, W1, W2, Wf1, Wf2);
    k_scan3<<<NB, SCAN_BLK, 0, stream>>>(degi, partials, rowptr, cursor);
    k_fill<<<(E + 255) / 256, 256, 0, stream>>>(src, dst, E, cursor, eidx);

    dim3 ggrid((NN + 127) / 128);  // 782, single column pass (BN=256)
    // layer 1: H1 = ns.(X @ W1)  (scale in epilogue)
    k_mfgemm<true><<<ggrid, 512, 0, stream>>>(features, norm_src, Wf1, Hbf);
    k_spmm_bf<<<(NN + 3) / 4, 256, 0, stream>>>(Hbf, rowptr, eidx, norm_dst,
                                                norm_src, b1, Xbf, out, 1);
    // layer 2
    k_mfgemm<false><<<ggrid, 512, 0, stream>>>(Xbf, nullptr, Wf2, Hbf);
    k_spmm_bf<<<(NN + 3) / 4, 256, 0, stream>>>(Hbf, rowptr, eidx, norm_dst,
                                                norm_src, b2, nullptr, out, 0);
}

// Round 14
// 371.986 us; speedup vs baseline: 1.0484x; 1.0484x over previous
//
#include <hip/hip_runtime.h>

#define NN 100000
#define DD 256
#define SCAN_BLK 1024

typedef unsigned int uint;
typedef unsigned short ushort;
typedef __attribute__((ext_vector_type(8))) short bfx8;
typedef __attribute__((ext_vector_type(4))) float fx4;

__device__ __forceinline__ ushort f2bf(float f) {  // RNE
    uint u = __float_as_uint(f);
    u += 0x7fff + ((u >> 16) & 1);
    return (ushort)(u >> 16);
}

__device__ __forceinline__ uint cvtpk(float lo, float hi) {  // 2xf32 -> packed bf16
    uint r;
    asm("v_cvt_pk_bf16_f32 %0, %1, %2" : "=v"(r) : "v"(lo), "v"(hi));
    return r;
}

// ---------------- degree count (deg arrays memset to 0 host-side) ----------
__global__ __launch_bounds__(256) void k_count(const int* __restrict__ src,
                                               const int* __restrict__ dst, int E,
                                               int* __restrict__ dego,
                                               int* __restrict__ degi) {
    int e = blockIdx.x * 256 + threadIdx.x;
    if (e < E) {
        atomicAdd(&dego[src[e]], 1);
        atomicAdd(&degi[dst[e]], 1);
    }
}

// ---------------- CSR build (scan by dst; degi = real in-edges) -------------
__device__ __forceinline__ int block_scan_inc(int v, int* sm) {
    int t = threadIdx.x;
    sm[t] = v;
    __syncthreads();
    for (int o = 1; o < SCAN_BLK; o <<= 1) {
        int x = (t >= o) ? sm[t - o] : 0;
        __syncthreads();
        sm[t] += x;
        __syncthreads();
    }
    return sm[t];
}

// scan1 fused with norm computation
__global__ __launch_bounds__(SCAN_BLK) void k_scan1n(const int* __restrict__ degi,
                                                     const int* __restrict__ dego,
                                                     int* __restrict__ partials,
                                                     float* __restrict__ ns,
                                                     float* __restrict__ nd) {
    __shared__ int sm[SCAN_BLK];
    int i = blockIdx.x * SCAN_BLK + threadIdx.x;
    int v = (i < NN) ? degi[i] : 0;
    if (i < NN) {
        ns[i] = rsqrtf((float)(dego[i] + 1));  // +1 = self-loop
        nd[i] = rsqrtf((float)(v + 1));
    }
    block_scan_inc(v, sm);
    if (threadIdx.x == 0) partials[blockIdx.x] = sm[SCAN_BLK - 1];
}

// scan2 fused with the W -> fragment-order Wf permutation (block 0 scans,
// blocks 1..64 convert). Wf: frag (c16,kf) = cols c16*16..+15, k kf*32..+31;
// lane l owns col c16*16+(l&15), k kf*32+(l>>4)*8..+7, at Wf[((c16*8+kf)*64+l)*8].
// A wave's bfx8 B-load is 64 lanes x 16 B CONTIGUOUS (1 KB burst).
__global__ __launch_bounds__(256) void k_scan2cw(int* __restrict__ partials, int nb,
                                                 const float* __restrict__ W1,
                                                 const float* __restrict__ W2,
                                                 ushort* __restrict__ Wf1,
                                                 ushort* __restrict__ Wf2) {
    if (blockIdx.x == 0) {
        __shared__ int sm[128];
        int t = threadIdx.x;
        int v = (t < 128 && t < nb) ? partials[t] : 0;
        if (t < 128) sm[t] = v;
        __syncthreads();
        for (int o = 1; o < 128; o <<= 1) {
            int x = (t < 128 && t >= o) ? sm[t - o] : 0;
            __syncthreads();
            if (t < 128) sm[t] += x;
            __syncthreads();
        }
        if (t < nb) partials[t] = sm[t] - v;  // exclusive
    } else {
        int tid = (blockIdx.x - 1) * 256 + threadIdx.x;  // 0..16383
        int m = tid >> 13;
        int r = tid & 8191;
        int lane = r & 63;
        int kf = (r >> 6) & 7;
        int c16 = r >> 9;
        int n = c16 * 16 + (lane & 15);
        int kb = kf * 32 + (lane >> 4) * 8;
        const float* W = m ? W2 : W1;
        ushort* Wf = m ? Wf2 : Wf1;
        uint4 u;
        u.x = (uint)f2bf(W[(size_t)(kb + 0) * DD + n]) |
              ((uint)f2bf(W[(size_t)(kb + 1) * DD + n]) << 16);
        u.y = (uint)f2bf(W[(size_t)(kb + 2) * DD + n]) |
              ((uint)f2bf(W[(size_t)(kb + 3) * DD + n]) << 16);
        u.z = (uint)f2bf(W[(size_t)(kb + 4) * DD + n]) |
              ((uint)f2bf(W[(size_t)(kb + 5) * DD + n]) << 16);
        u.w = (uint)f2bf(W[(size_t)(kb + 6) * DD + n]) |
              ((uint)f2bf(W[(size_t)(kb + 7) * DD + n]) << 16);
        *(uint4*)&Wf[(size_t)r * 8] = u;
    }
}

__global__ __launch_bounds__(SCAN_BLK) void k_scan3(const int* __restrict__ degi,
                                                    const int* __restrict__ partials,
                                                    int* __restrict__ rowptr,
                                                    int* __restrict__ cursor) {
    __shared__ int sm[SCAN_BLK];
    int i = blockIdx.x * SCAN_BLK + threadIdx.x;
    int v = (i < NN) ? degi[i] : 0;
    int incl = block_scan_inc(v, sm);
    int excl = partials[blockIdx.x] + incl - v;
    if (i <= NN) rowptr[i] = excl;   // rowptr[NN] = E
    if (i < NN) cursor[i] = excl;
}

__global__ __launch_bounds__(256) void k_fill(const int* __restrict__ src,
                                              const int* __restrict__ dst, int E,
                                              int* __restrict__ cursor,
                                              int* __restrict__ eidx) {
    int e = blockIdx.x * 256 + threadIdx.x;
    if (e < E) {
        int d = dst[e];
        int p = atomicAdd(&cursor[d], 1);
        eidx[p] = src[e];
    }
}

// ---------------- MFMA GEMM: H = A @ W (optionally row-scaled) -------------
// SMALL-BLOCK GEOMETRY: 64x256 tile, 256 threads (4 waves, wave w owns cols
// w*64..+63), whole 32 KB A-tile staged up front, one drain, barrier-free
// 64-MFMA K-loop, LDS epilogue in the same 32 KB. Rationale (cross-round
// evidence): r3's 256-thread/many-block GEMM sustained 3.3 TB/s; every
// 512-thread 2-blocks/CU variant (r6-r13) got 0.7-1.8 TB/s at 6% MfmaUtil —
// big blocks serialize stage->drain->compute->epilogue phases and 2 lockstep
// blocks/CU can't keep the memory pipe busy. 4 independent blocks/CU
// (launch_bounds(256,4), 32 KB LDS) restores phase-staggered memory overlap.
//   FP32A:  reg-staged (ping-pong named groups), cvt_pk, swizzled ds_write;
//           row scale nrm applied in the epilogue.
//   !FP32A: global_load_lds direct (pre-swizzled source, linear dest).
// B from fragment-order Wf (L2-resident, 1 KB coalesced bursts).
template <bool FP32A>
__global__ __launch_bounds__(256, 4) void k_mfgemm(const void* __restrict__ Av,
                                                   const float* __restrict__ nrm,
                                                   const ushort* __restrict__ Wf,
                                                   ushort* __restrict__ H) {
    __shared__ uint4 atq[2048];  // whole A-tile bf16: [ks][64 r][8 ch] = 32 KB
    int t = threadIdx.x;
    int brow = blockIdx.x * 64;
    int lane = t & 63, w = t >> 6;     // 4 waves; wave w -> cols w*64..+63
    int lg = lane >> 4, lr = lane & 15;

    // ---- stage the whole tile (slot s = g*256+t: ks=s>>9, r=(s&511)>>3, ch=s&7;
    //      linear dest slot s, source chunk pre-swizzled cs=ch^(r&7)) ----
    if (FP32A) {
        const float* X = (const float*)Av;
        float4 ga[2], gb[2];
        auto ldG = [&](int g, float4* sv) {
            int s = g * 256 + t;
            int ks = s >> 9, r = (s & 511) >> 3;
            int cs = (s & 7) ^ (r & 7);
            int row = brow + r;
            if (row >= NN) row = NN - 1;  // tail clamp (stores masked)
            const float4* p4 = (const float4*)(X + (size_t)row * DD + ks * 64 + cs * 8);
            sv[0] = p4[0];
            sv[1] = p4[1];
        };
        auto wrG = [&](int g, const float4* sv) {
            int s = g * 256 + t;
            uint4 u;
            u.x = cvtpk(sv[0].x, sv[0].y);
            u.y = cvtpk(sv[0].z, sv[0].w);
            u.z = cvtpk(sv[1].x, sv[1].y);
            u.w = cvtpk(sv[1].z, sv[1].w);
            atq[s] = u;
        };
        ldG(0, ga); ldG(1, gb);
        wrG(0, ga); ldG(2, ga);
        wrG(1, gb); ldG(3, gb);
        wrG(2, ga); ldG(4, ga);
        wrG(3, gb); ldG(5, gb);
        wrG(4, ga); ldG(6, ga);
        wrG(5, gb); ldG(7, gb);
        wrG(6, ga);
        wrG(7, gb);
    } else {
#pragma unroll
        for (int i = 0; i < 8; ++i) {
            int s = i * 256 + w * 64 + lane;     // this lane's dest slot
            int ks = s >> 9, r = (s & 511) >> 3;
            int cs = (s & 7) ^ (r & 7);          // inverse swizzle on source
            int row = brow + r;
            if (row >= NN) row = NN - 1;
            const ushort* g = (const ushort*)Av + (size_t)row * DD + ks * 64 + cs * 8;
            __builtin_amdgcn_global_load_lds(
                (const __attribute__((address_space(1))) uint*)g,
                (__attribute__((address_space(3))) uint*)&atq[i * 256 + w * 64],
                16, 0, 0);
        }
    }

    // ---- B: fragment-order, coalesced 1 KB bursts (wave w -> c16 = w*4+ni) --
    bfx8 bfr2[2][4];
    auto ldB = [&](int ks) {
#pragma unroll
        for (int kk = 0; kk < 2; ++kk)
#pragma unroll
            for (int ni = 0; ni < 4; ++ni)
                bfr2[kk][ni] = *(const bfx8*)&Wf[
                    (((size_t)(w * 4 + ni) * 8 + (ks * 2 + kk)) * 64 + lane) * 8];
    };
    ldB(0);

    fx4 acc[4][4];
#pragma unroll
    for (int mi = 0; mi < 4; ++mi)
#pragma unroll
        for (int ni = 0; ni < 4; ++ni)
            acc[mi][ni] = (fx4){0.f, 0.f, 0.f, 0.f};

    __syncthreads();  // the ONE staging drain

    // ---- barrier-free K-loop: 64 MFMAs ----
#pragma unroll
    for (int ks = 0; ks < 4; ++ks) {
#pragma unroll
        for (int kk = 0; kk < 2; ++kk)
#pragma unroll
            for (int mi = 0; mi < 4; ++mi) {
                int r = mi * 16 + lr;
                int c = kk * 4 + lg;
                bfx8 af = *(const bfx8*)&atq[ks * 512 + r * 8 + (c ^ (r & 7))];
#pragma unroll
                for (int ni = 0; ni < 4; ++ni)
                    acc[mi][ni] = __builtin_amdgcn_mfma_f32_16x16x32_bf16(
                        af, bfr2[kk][ni], acc[mi][ni], 0, 0, 0);
            }
        if (ks < 3) ldB(ks + 1);  // after last consumer of bfr2
    }

    __syncthreads();  // all tile reads complete; atq reusable

    // ---- epilogue: 64x256 tile via LDS, coalesced uint4 stores ----
    float scl[4][4];
    if (FP32A) {
#pragma unroll
        for (int mi = 0; mi < 4; ++mi)
#pragma unroll
            for (int j = 0; j < 4; ++j) {
                int row = brow + mi * 16 + lg * 4 + j;
                scl[mi][j] = nrm[row < NN ? row : NN - 1];
            }
    }
    ushort* hs = (ushort*)atq;  // 64 rows x 256 ushorts = 32 KB
#pragma unroll
    for (int mi = 0; mi < 4; ++mi)
#pragma unroll
        for (int ni = 0; ni < 4; ++ni)
#pragma unroll
            for (int j = 0; j < 4; ++j) {
                int r = mi * 16 + lg * 4 + j;       // 0..63
                int c = w * 64 + ni * 16 + lr;
                float v = acc[mi][ni][j];
                if (FP32A) v *= scl[mi][j];
                hs[r * 256 + (((c >> 3) ^ (r & 7)) << 3) + (c & 7)] = f2bf(v);
            }
    __syncthreads();
    {
        int rl = t >> 2;               // 0..63, 4 threads/row
        int grow = brow + rl;
        if (grow < NN) {
            ushort* hp = H + (size_t)grow * DD;
#pragma unroll
            for (int i = 0; i < 8; ++i) {
                int ch = (t & 3) * 8 + i;
                uint4 v = *(const uint4*)&hs[rl * 256 + ((ch ^ (rl & 7)) << 3)];
                *(uint4*)(hp + ch * 8) = v;
            }
        }
    }
}

// ---------------- SpMM (bf16 gather, fp32 accum): one wave per dst node ----
__global__ __launch_bounds__(256) void k_spmm_bf(const ushort* __restrict__ T,
                                                 const int* __restrict__ rowptr,
                                                 const int* __restrict__ eidx,
                                                 const float* __restrict__ nd,
                                                 const float* __restrict__ ns,
                                                 const float* __restrict__ bias,
                                                 ushort* __restrict__ obf,
                                                 float* __restrict__ of,
                                                 int layer1) {
    int wid = threadIdx.x >> 6, lane = threadIdx.x & 63;
    int node = blockIdx.x * 4 + wid;
    if (node >= NN) return;
    int c = lane << 2;  // 4 bf16 per lane
    uint2 sv = *(const uint2*)(T + (size_t)node * DD + c);  // self-loop
    float p0[4], p1[4], p2[4], p3[4];
    p0[0] = __uint_as_float(sv.x << 16);
    p0[1] = __uint_as_float(sv.x & 0xffff0000u);
    p0[2] = __uint_as_float(sv.y << 16);
    p0[3] = __uint_as_float(sv.y & 0xffff0000u);
#pragma unroll
    for (int j = 0; j < 4; ++j) { p1[j] = 0.f; p2[j] = 0.f; p3[j] = 0.f; }
    int e = rowptr[node], end = rowptr[node + 1];
    for (; e + 3 < end; e += 4) {
        int s0 = eidx[e], s1 = eidx[e + 1], s2 = eidx[e + 2], s3 = eidx[e + 3];
        uint2 v0 = *(const uint2*)(T + (size_t)s0 * DD + c);
        uint2 v1 = *(const uint2*)(T + (size_t)s1 * DD + c);
        uint2 v2 = *(const uint2*)(T + (size_t)s2 * DD + c);
        uint2 v3 = *(const uint2*)(T + (size_t)s3 * DD + c);
        p0[0] += __uint_as_float(v0.x << 16);
        p0[1] += __uint_as_float(v0.x & 0xffff0000u);
        p0[2] += __uint_as_float(v0.y << 16);
        p0[3] += __uint_as_float(v0.y & 0xffff0000u);
        p1[0] += __uint_as_float(v1.x << 16);
        p1[1] += __uint_as_float(v1.x & 0xffff0000u);
        p1[2] += __uint_as_float(v1.y << 16);
        p1[3] += __uint_as_float(v1.y & 0xffff0000u);
        p2[0] += __uint_as_float(v2.x << 16);
        p2[1] += __uint_as_float(v2.x & 0xffff0000u);
        p2[2] += __uint_as_float(v2.y << 16);
        p2[3] += __uint_as_float(v2.y & 0xffff0000u);
        p3[0] += __uint_as_float(v3.x << 16);
        p3[1] += __uint_as_float(v3.x & 0xffff0000u);
        p3[2] += __uint_as_float(v3.y << 16);
        p3[3] += __uint_as_float(v3.y & 0xffff0000u);
    }
    for (; e < end; ++e) {
        int s0 = eidx[e];
        uint2 v0 = *(const uint2*)(T + (size_t)s0 * DD + c);
        p0[0] += __uint_as_float(v0.x << 16);
        p0[1] += __uint_as_float(v0.x & 0xffff0000u);
        p0[2] += __uint_as_float(v0.y << 16);
        p0[3] += __uint_as_float(v0.y & 0xffff0000u);
    }
#pragma unroll
    for (int j = 0; j < 4; ++j) p0[j] += (p1[j] + p2[j]) + p3[j];
    float n = nd[node];
    float4 bb = *(const float4*)(bias + c);
    float o0 = fmaf(p0[0], n, bb.x);
    float o1 = fmaf(p0[1], n, bb.y);
    float o2 = fmaf(p0[2], n, bb.z);
    float o3 = fmaf(p0[3], n, bb.w);
    if (layer1) {
        float s = ns[node];
        o0 = fmaxf(o0, 0.f) * s; o1 = fmaxf(o1, 0.f) * s;
        o2 = fmaxf(o2, 0.f) * s; o3 = fmaxf(o3, 0.f) * s;
        uint lo = (uint)f2bf(o0) | ((uint)f2bf(o1) << 16);
        uint hi = (uint)f2bf(o2) | ((uint)f2bf(o3) << 16);
        *(uint2*)(obf + (size_t)node * DD + c) = make_uint2(lo, hi);
    } else {
        fx4 o = {o0, o1, o2, o3};
        __builtin_nontemporal_store(o, (fx4*)(of + (size_t)node * DD + c));
    }
}

extern "C" void kernel_launch(void* const* d_in, const int* in_sizes, int n_in,
                              void* d_out, int out_size, void* d_ws, size_t ws_size,
                              hipStream_t stream) {
    const float* features = (const float*)d_in[0];
    const int* src = (const int*)d_in[1];
    const int* dst = (const int*)d_in[2];
    const float* W1 = (const float*)d_in[3];
    const float* b1 = (const float*)d_in[4];
    const float* W2 = (const float*)d_in[5];
    const float* b2 = (const float*)d_in[6];
    int E = in_sizes[1];
    float* out = (float*)d_out;

    size_t off = 0;
    auto alloc = [&](size_t nbytes) -> void* {
        void* p = (char*)d_ws + off;
        off += (nbytes + 255) & ~(size_t)255;
        return p;
    };
    int* dego = (int*)alloc((size_t)NN * 4);      // offset 0
    int* degi = (int*)alloc((size_t)NN * 4);      // offset 400128 (contiguous)
    float* norm_src = (float*)alloc((size_t)NN * 4);
    float* norm_dst = (float*)alloc((size_t)NN * 4);
    int* rowptr = (int*)alloc((size_t)(NN + 1) * 4);
    int* cursor = (int*)alloc((size_t)NN * 4);
    int* partials = (int*)alloc(128 * 4);
    int* eidx = (int*)alloc((size_t)E * 4);
    ushort* Wf1 = (ushort*)alloc((size_t)DD * DD * 2);
    ushort* Wf2 = (ushort*)alloc((size_t)DD * DD * 2);
    ushort* Xbf = (ushort*)alloc((size_t)NN * DD * 2);
    ushort* Hbf = (ushort*)alloc((size_t)NN * DD * 2);

    const int NB = (NN + SCAN_BLK - 1) / SCAN_BLK;  // 98

    hipMemsetAsync(dego, 0, (size_t)2 * 400128, stream);  // dego+degi adjacent
    k_count<<<(E + 255) / 256, 256, 0, stream>>>(src, dst, E, dego, degi);
    k_scan1n<<<NB, SCAN_BLK, 0, stream>>>(degi, dego, partials, norm_src, norm_dst);
    k_scan2cw<<<65, 256, 0, stream>>>(partials, NB, W1, W2, Wf1, Wf2);
    k_scan3<<<NB, SCAN_BLK, 0, stream>>>(degi, partials, rowptr, cursor);
    k_fill<<<(E + 255) / 256, 256, 0, stream>>>(src, dst, E, cursor, eidx);

    dim3 ggrid((NN + 63) / 64);  // 1563 blocks of 256 threads
    // layer 1: H1 = ns.(X @ W1)  (scale in epilogue)
    k_mfgemm<true><<<ggrid, 256, 0, stream>>>(features, norm_src, Wf1, Hbf);
    k_spmm_bf<<<(NN + 3) / 4, 256, 0, stream>>>(Hbf, rowptr, eidx, norm_dst,
                                                norm_src, b1, Xbf, out, 1);
    // layer 2
    k_mfgemm<false><<<ggrid, 256, 0, stream>>>(Xbf, nullptr, Wf2, Hbf);
    k_spmm_bf<<<(NN + 3) / 4, 256, 0, stream>>>(Hbf, rowptr, eidx, norm_dst,
                                                norm_src, b2, nullptr, out, 0);
}

// Round 15
// 356.263 us; speedup vs baseline: 1.0946x; 1.0441x over previous
//
#include <hip/hip_runtime.h>

#define NN 100000
#define DD 256
#define SCAN_BLK 1024

typedef unsigned int uint;
typedef unsigned short ushort;
typedef __attribute__((ext_vector_type(8))) short bfx8;
typedef __attribute__((ext_vector_type(4))) float fx4;

__device__ __forceinline__ ushort f2bf(float f) {  // RNE
    uint u = __float_as_uint(f);
    u += 0x7fff + ((u >> 16) & 1);
    return (ushort)(u >> 16);
}

__device__ __forceinline__ uint cvtpk(float lo, float hi) {  // 2xf32 -> packed bf16
    uint r;
    asm("v_cvt_pk_bf16_f32 %0, %1, %2" : "=v"(r) : "v"(lo), "v"(hi));
    return r;
}

// ---------------- degree count (deg arrays memset to 0 host-side) ----------
__global__ __launch_bounds__(256) void k_count(const int* __restrict__ src,
                                               const int* __restrict__ dst, int E,
                                               int* __restrict__ dego,
                                               int* __restrict__ degi) {
    int e = blockIdx.x * 256 + threadIdx.x;
    if (e < E) {
        atomicAdd(&dego[src[e]], 1);
        atomicAdd(&degi[dst[e]], 1);
    }
}

// ---------------- CSR build (scan by dst; degi = real in-edges) -------------
// shfl-based block scan: 6 shuffle steps in-wave (no barriers) + 16-partial
// LDS scan by wave 0 + offset add. 2 barriers vs the old Hillis-Steele's 20.
__device__ __forceinline__ int block_scan_inc(int v, int* wsum) {
    int lane = threadIdx.x & 63, wid = threadIdx.x >> 6;
#pragma unroll
    for (int o = 1; o < 64; o <<= 1) {
        int u = __shfl_up(v, o);
        if (lane >= o) v += u;
    }
    if (lane == 63) wsum[wid] = v;
    __syncthreads();
    if (wid == 0) {
        int s = (lane < 16) ? wsum[lane] : 0;
#pragma unroll
        for (int o = 1; o < 16; o <<= 1) {
            int u = __shfl_up(s, o);
            if (lane >= o) s += u;
        }
        if (lane < 16) wsum[lane] = s;
    }
    __syncthreads();
    if (wid > 0) v += wsum[wid - 1];
    return v;
}

// scan1 fused with norm computation
__global__ __launch_bounds__(SCAN_BLK) void k_scan1n(const int* __restrict__ degi,
                                                     const int* __restrict__ dego,
                                                     int* __restrict__ partials,
                                                     float* __restrict__ ns,
                                                     float* __restrict__ nd) {
    __shared__ int wsum[16];
    int i = blockIdx.x * SCAN_BLK + threadIdx.x;
    int v = (i < NN) ? degi[i] : 0;
    if (i < NN) {
        ns[i] = rsqrtf((float)(dego[i] + 1));  // +1 = self-loop
        nd[i] = rsqrtf((float)(v + 1));
    }
    int incl = block_scan_inc(v, wsum);
    if (threadIdx.x == SCAN_BLK - 1) partials[blockIdx.x] = incl;
}

// scan2 fused with the W -> fragment-order Wf permutation (block 0 scans,
// blocks 1..64 convert). Wf: frag (c16,kf) = cols c16*16..+15, k kf*32..+31;
// lane l owns col c16*16+(l&15), k kf*32+(l>>4)*8..+7, at Wf[((c16*8+kf)*64+l)*8].
// A wave's bfx8 B-load is 64 lanes x 16 B CONTIGUOUS (1 KB burst).
__global__ __launch_bounds__(256) void k_scan2cw(int* __restrict__ partials, int nb,
                                                 const float* __restrict__ W1,
                                                 const float* __restrict__ W2,
                                                 ushort* __restrict__ Wf1,
                                                 ushort* __restrict__ Wf2) {
    if (blockIdx.x == 0) {
        __shared__ int sm[128];
        int t = threadIdx.x;
        int v = (t < 128 && t < nb) ? partials[t] : 0;
        if (t < 128) sm[t] = v;
        __syncthreads();
        for (int o = 1; o < 128; o <<= 1) {
            int x = (t < 128 && t >= o) ? sm[t - o] : 0;
            __syncthreads();
            if (t < 128) sm[t] += x;
            __syncthreads();
        }
        if (t < nb) partials[t] = sm[t] - v;  // exclusive
    } else {
        int tid = (blockIdx.x - 1) * 256 + threadIdx.x;  // 0..16383
        int m = tid >> 13;
        int r = tid & 8191;
        int lane = r & 63;
        int kf = (r >> 6) & 7;
        int c16 = r >> 9;
        int n = c16 * 16 + (lane & 15);
        int kb = kf * 32 + (lane >> 4) * 8;
        const float* W = m ? W2 : W1;
        ushort* Wf = m ? Wf2 : Wf1;
        uint4 u;
        u.x = (uint)f2bf(W[(size_t)(kb + 0) * DD + n]) |
              ((uint)f2bf(W[(size_t)(kb + 1) * DD + n]) << 16);
        u.y = (uint)f2bf(W[(size_t)(kb + 2) * DD + n]) |
              ((uint)f2bf(W[(size_t)(kb + 3) * DD + n]) << 16);
        u.z = (uint)f2bf(W[(size_t)(kb + 4) * DD + n]) |
              ((uint)f2bf(W[(size_t)(kb + 5) * DD + n]) << 16);
        u.w = (uint)f2bf(W[(size_t)(kb + 6) * DD + n]) |
              ((uint)f2bf(W[(size_t)(kb + 7) * DD + n]) << 16);
        *(uint4*)&Wf[(size_t)r * 8] = u;
    }
}

__global__ __launch_bounds__(SCAN_BLK) void k_scan3(const int* __restrict__ degi,
                                                    const int* __restrict__ partials,
                                                    int* __restrict__ rowptr,
                                                    int* __restrict__ cursor) {
    __shared__ int wsum[16];
    int i = blockIdx.x * SCAN_BLK + threadIdx.x;
    int v = (i < NN) ? degi[i] : 0;
    int incl = block_scan_inc(v, wsum);
    int excl = partials[blockIdx.x] + incl - v;
    if (i <= NN) rowptr[i] = excl;   // rowptr[NN] = E
    if (i < NN) cursor[i] = excl;
}

__global__ __launch_bounds__(256) void k_fill(const int* __restrict__ src,
                                              const int* __restrict__ dst, int E,
                                              int* __restrict__ cursor,
                                              int* __restrict__ eidx) {
    int e = blockIdx.x * 256 + threadIdx.x;
    if (e < E) {
        int d = dst[e];
        int p = atomicAdd(&cursor[d], 1);
        eidx[p] = src[e];
    }
}

// ---------------- MFMA GEMM: H = A @ W (optionally row-scaled) -------------
// r12 structure (best measured): tile 128x256, BK=64, 512 threads (8 waves
// 2x4), wave tile 64x64, 32 KB LDS A dbuf.
//   FP32A:  reg-staged — load f32, cvt_pk to bf16, ds_write swizzled;
//           row scale nrm applied in the epilogue.
//   !FP32A: global_load_lds direct (pre-swizzled source, linear dest).
// B from fragment-order Wf (L2-resident): per K-step all 8 frags preloaded
// as 1 KB coalesced bursts. Epilogue via LDS halves (coalesced stores).
template <bool FP32A>
__global__ __launch_bounds__(512, 4) void k_mfgemm(const void* __restrict__ Av,
                                                   const float* __restrict__ nrm,
                                                   const ushort* __restrict__ Wf,
                                                   ushort* __restrict__ H) {
    __shared__ uint4 atq[2][128 * 8];  // A tile bf16 [128r][8 chunks], dbuf, 32 KB
    int t = threadIdx.x;
    int brow = blockIdx.x * 128;
    int lane = t & 63, w = t >> 6;
    int wr = w >> 2, wc = w & 3;       // wave grid 2x4
    int lg = lane >> 4, lr = lane & 15;

    // ---- A staging setup ----
    int sr = t >> 3, sc = t & 7;       // reg-staging coords (FP32A)
    int rows_[2];
#pragma unroll
    for (int i = 0; i < 2; ++i) {
        int r = brow + sr + i * 64;
        rows_[i] = (r < NN) ? r : NN - 1;  // tail clamp (stores masked)
    }
    float4 svf[2][2];
    uint gofs[2];                      // gload_lds coords (!FP32A)
    if (!FP32A) {
#pragma unroll
        for (int i = 0; i < 2; ++i) {
            int slot = (w * 2 + i) * 64;
            int r = slot / 8 + lane / 8;
            int cs = (lane & 7) ^ (r & 7);
            int row = brow + r;
            if (row >= NN) row = NN - 1;
            gofs[i] = (uint)(((size_t)row * DD + cs * 8) * 2);
        }
    }

    auto ldA = [&](int ks) {  // FP32A: issue global loads early
        const float* X = (const float*)Av;
#pragma unroll
        for (int i = 0; i < 2; ++i) {
            const float4* p =
                (const float4*)(X + (size_t)rows_[i] * DD + ks * 64 + sc * 8);
            svf[i][0] = p[0];
            svf[i][1] = p[1];
        }
    };
    auto wrA = [&](int buf) {  // FP32A: convert + swizzled LDS write (late)
#pragma unroll
        for (int i = 0; i < 2; ++i) {
            int r = sr + i * 64;
            uint4 u;
            u.x = cvtpk(svf[i][0].x, svf[i][0].y);
            u.y = cvtpk(svf[i][0].z, svf[i][0].w);
            u.z = cvtpk(svf[i][1].x, svf[i][1].y);
            u.w = cvtpk(svf[i][1].z, svf[i][1].w);
            atq[buf][r * 8 + (sc ^ (r & 7))] = u;
        }
    };
    auto stage = [&](int buf, int ks) {  // !FP32A: async direct-to-LDS
#pragma unroll
        for (int i = 0; i < 2; ++i) {
            int slot = (w * 2 + i) * 64;
            const char* g = (const char*)Av + gofs[i] + ks * 128;
            __builtin_amdgcn_global_load_lds(
                (const __attribute__((address_space(1))) uint*)g,
                (__attribute__((address_space(3))) uint*)&atq[buf][slot], 16, 0, 0);
        }
    };

    // ---- B: fragment-order, coalesced 1 KB bursts ----
    bfx8 bfr2[2][4];
    auto ldB = [&](int ks) {
#pragma unroll
        for (int kk = 0; kk < 2; ++kk)
#pragma unroll
            for (int ni = 0; ni < 4; ++ni)
                bfr2[kk][ni] = *(const bfx8*)&Wf[
                    (((size_t)(wc * 4 + ni) * 8 + (ks * 2 + kk)) * 64 + lane) * 8];
    };

    fx4 acc[4][4];
#pragma unroll
    for (int mi = 0; mi < 4; ++mi)
#pragma unroll
        for (int ni = 0; ni < 4; ++ni)
            acc[mi][ni] = (fx4){0.f, 0.f, 0.f, 0.f};

    if (FP32A) { ldA(0); wrA(0); } else stage(0, 0);
    ldB(0);
    __syncthreads();

    int buf = 0;
#pragma unroll
    for (int ks = 0; ks < 4; ++ks) {
        if (ks < 3) {
            if (FP32A) ldA(ks + 1);      // issue early: hide under MFMA
            else stage(buf ^ 1, ks + 1); // async into other buffer
        }
#pragma unroll
        for (int kk = 0; kk < 2; ++kk) {
#pragma unroll
            for (int mi = 0; mi < 4; ++mi) {
                int r = wr * 64 + mi * 16 + lr;
                int c = kk * 4 + lg;
                bfx8 af = *(const bfx8*)&atq[buf][r * 8 + (c ^ (r & 7))];
#pragma unroll
                for (int ni = 0; ni < 4; ++ni)
                    acc[mi][ni] = __builtin_amdgcn_mfma_f32_16x16x32_bf16(
                        af, bfr2[kk][ni], acc[mi][ni], 0, 0, 0);
            }
        }
        if (ks < 3) {
            if (FP32A) wrA(buf ^ 1);     // write late, other buffer
            ldB(ks + 1);                 // after last consumer of bfr2
        }
        __syncthreads();
        buf ^= 1;
    }
    // K-loop ends with a barrier: staging reads complete, atq reusable.

    // ---- epilogue via LDS, two 64-row halves (coalesced 16B stores) ----
    float scl[4][4];
    if (FP32A) {
#pragma unroll
        for (int mi = 0; mi < 4; ++mi)
#pragma unroll
            for (int j = 0; j < 4; ++j) {
                int row = brow + wr * 64 + mi * 16 + lg * 4 + j;
                scl[mi][j] = nrm[row < NN ? row : NN - 1];
            }
    }
    ushort* hs = (ushort*)&atq[0][0];  // 64 rows x 256 ushorts = 32 KB
#pragma unroll
    for (int h = 0; h < 2; ++h) {
        if (wr == h) {
#pragma unroll
            for (int mi = 0; mi < 4; ++mi)
#pragma unroll
                for (int ni = 0; ni < 4; ++ni)
#pragma unroll
                    for (int j = 0; j < 4; ++j) {
                        int rl = mi * 16 + lg * 4 + j;   // 0..63 within half
                        int c = wc * 64 + ni * 16 + lr;
                        float v = acc[mi][ni][j];
                        if (FP32A) v *= scl[mi][j];
                        hs[rl * 256 + (((c >> 3) ^ (rl & 7)) << 3) + (c & 7)] =
                            f2bf(v);
                    }
        }
        __syncthreads();
        {
            int rl = t >> 3;               // 0..63
            int grow = brow + h * 64 + rl;
            if (grow < NN) {
                ushort* hp = H + (size_t)grow * DD;
#pragma unroll
                for (int i = 0; i < 4; ++i) {
                    int ch = (t & 7) + i * 8;
                    uint4 v = *(const uint4*)&hs[rl * 256 + ((ch ^ (rl & 7)) << 3)];
                    *(uint4*)(hp + ch * 8) = v;
                }
            }
        }
        __syncthreads();
    }
}

// ---------------- SpMM (bf16 gather, fp32 accum): one wave per dst node ----
__global__ __launch_bounds__(256) void k_spmm_bf(const ushort* __restrict__ T,
                                                 const int* __restrict__ rowptr,
                                                 const int* __restrict__ eidx,
                                                 const float* __restrict__ nd,
                                                 const float* __restrict__ ns,
                                                 const float* __restrict__ bias,
                                                 ushort* __restrict__ obf,
                                                 float* __restrict__ of,
                                                 int layer1) {
    int wid = threadIdx.x >> 6, lane = threadIdx.x & 63;
    int node = blockIdx.x * 4 + wid;
    if (node >= NN) return;
    int c = lane << 2;  // 4 bf16 per lane
    uint2 sv = *(const uint2*)(T + (size_t)node * DD + c);  // self-loop
    float p0[4], p1[4], p2[4], p3[4];
    p0[0] = __uint_as_float(sv.x << 16);
    p0[1] = __uint_as_float(sv.x & 0xffff0000u);
    p0[2] = __uint_as_float(sv.y << 16);
    p0[3] = __uint_as_float(sv.y & 0xffff0000u);
#pragma unroll
    for (int j = 0; j < 4; ++j) { p1[j] = 0.f; p2[j] = 0.f; p3[j] = 0.f; }
    int e = rowptr[node], end = rowptr[node + 1];
    for (; e + 3 < end; e += 4) {
        int s0 = eidx[e], s1 = eidx[e + 1], s2 = eidx[e + 2], s3 = eidx[e + 3];
        uint2 v0 = *(const uint2*)(T + (size_t)s0 * DD + c);
        uint2 v1 = *(const uint2*)(T + (size_t)s1 * DD + c);
        uint2 v2 = *(const uint2*)(T + (size_t)s2 * DD + c);
        uint2 v3 = *(const uint2*)(T + (size_t)s3 * DD + c);
        p0[0] += __uint_as_float(v0.x << 16);
        p0[1] += __uint_as_float(v0.x & 0xffff0000u);
        p0[2] += __uint_as_float(v0.y << 16);
        p0[3] += __uint_as_float(v0.y & 0xffff0000u);
        p1[0] += __uint_as_float(v1.x << 16);
        p1[1] += __uint_as_float(v1.x & 0xffff0000u);
        p1[2] += __uint_as_float(v1.y << 16);
        p1[3] += __uint_as_float(v1.y & 0xffff0000u);
        p2[0] += __uint_as_float(v2.x << 16);
        p2[1] += __uint_as_float(v2.x & 0xffff0000u);
        p2[2] += __uint_as_float(v2.y << 16);
        p2[3] += __uint_as_float(v2.y & 0xffff0000u);
        p3[0] += __uint_as_float(v3.x << 16);
        p3[1] += __uint_as_float(v3.x & 0xffff0000u);
        p3[2] += __uint_as_float(v3.y << 16);
        p3[3] += __uint_as_float(v3.y & 0xffff0000u);
    }
    for (; e < end; ++e) {
        int s0 = eidx[e];
        uint2 v0 = *(const uint2*)(T + (size_t)s0 * DD + c);
        p0[0] += __uint_as_float(v0.x << 16);
        p0[1] += __uint_as_float(v0.x & 0xffff0000u);
        p0[2] += __uint_as_float(v0.y << 16);
        p0[3] += __uint_as_float(v0.y & 0xffff0000u);
    }
#pragma unroll
    for (int j = 0; j < 4; ++j) p0[j] += (p1[j] + p2[j]) + p3[j];
    float n = nd[node];
    float4 bb = *(const float4*)(bias + c);
    float o0 = fmaf(p0[0], n, bb.x);
    float o1 = fmaf(p0[1], n, bb.y);
    float o2 = fmaf(p0[2], n, bb.z);
    float o3 = fmaf(p0[3], n, bb.w);
    if (layer1) {
        float s = ns[node];
        o0 = fmaxf(o0, 0.f) * s; o1 = fmaxf(o1, 0.f) * s;
        o2 = fmaxf(o2, 0.f) * s; o3 = fmaxf(o3, 0.f) * s;
        uint lo = (uint)f2bf(o0) | ((uint)f2bf(o1) << 16);
        uint hi = (uint)f2bf(o2) | ((uint)f2bf(o3) << 16);
        *(uint2*)(obf + (size_t)node * DD + c) = make_uint2(lo, hi);
    } else {
        fx4 o = {o0, o1, o2, o3};
        __builtin_nontemporal_store(o, (fx4*)(of + (size_t)node * DD + c));
    }
}

extern "C" void kernel_launch(void* const* d_in, const int* in_sizes, int n_in,
                              void* d_out, int out_size, void* d_ws, size_t ws_size,
                              hipStream_t stream) {
    const float* features = (const float*)d_in[0];
    const int* src = (const int*)d_in[1];
    const int* dst = (const int*)d_in[2];
    const float* W1 = (const float*)d_in[3];
    const float* b1 = (const float*)d_in[4];
    const float* W2 = (const float*)d_in[5];
    const float* b2 = (const float*)d_in[6];
    int E = in_sizes[1];
    float* out = (float*)d_out;

    size_t off = 0;
    auto alloc = [&](size_t nbytes) -> void* {
        void* p = (char*)d_ws + off;
        off += (nbytes + 255) & ~(size_t)255;
        return p;
    };
    int* dego = (int*)alloc((size_t)NN * 4);      // offset 0
    int* degi = (int*)alloc((size_t)NN * 4);      // offset 400128 (contiguous)
    float* norm_src = (float*)alloc((size_t)NN * 4);
    float* norm_dst = (float*)alloc((size_t)NN * 4);
    int* rowptr = (int*)alloc((size_t)(NN + 1) * 4);
    int* cursor = (int*)alloc((size_t)NN * 4);
    int* partials = (int*)alloc(128 * 4);
    int* eidx = (int*)alloc((size_t)E * 4);
    ushort* Wf1 = (ushort*)alloc((size_t)DD * DD * 2);
    ushort* Wf2 = (ushort*)alloc((size_t)DD * DD * 2);
    ushort* Xbf = (ushort*)alloc((size_t)NN * DD * 2);
    ushort* Hbf = (ushort*)alloc((size_t)NN * DD * 2);

    const int NB = (NN + SCAN_BLK - 1) / SCAN_BLK;  // 98

    hipMemsetAsync(dego, 0, (size_t)2 * 400128, stream);  // dego+degi adjacent
    k_count<<<(E + 255) / 256, 256, 0, stream>>>(src, dst, E, dego, degi);
    k_scan1n<<<NB, SCAN_BLK, 0, stream>>>(degi, dego, partials, norm_src, norm_dst);
    k_scan2cw<<<65, 256, 0, stream>>>(partials, NB, W1, W2, Wf1, Wf2);
    k_scan3<<<NB, SCAN_BLK, 0, stream>>>(degi, partials, rowptr, cursor);
    k_fill<<<(E + 255) / 256, 256, 0, stream>>>(src, dst, E, cursor, eidx);

    dim3 ggrid((NN + 127) / 128);  // 782, single column pass (BN=256)
    // layer 1: H1 = ns.(X @ W1)  (scale in epilogue)
    k_mfgemm<true><<<ggrid, 512, 0, stream>>>(features, norm_src, Wf1, Hbf);
    k_spmm_bf<<<(NN + 3) / 4, 256, 0, stream>>>(Hbf, rowptr, eidx, norm_dst,
                                                norm_src, b1, Xbf, out, 1);
    // layer 2
    k_mfgemm<false><<<ggrid, 512, 0, stream>>>(Xbf, nullptr, Wf2, Hbf);
    k_spmm_bf<<<(NN + 3) / 4, 256, 0, stream>>>(Hbf, rowptr, eidx, norm_dst,
                                                norm_src, b2, nullptr, out, 0);
}

// Round 16
// 354.123 us; speedup vs baseline: 1.1012x; 1.0060x over previous
//
#include <hip/hip_runtime.h>

#define NN 100000
#define DD 256
#define SCAN_BLK 1024

typedef unsigned int uint;
typedef unsigned short ushort;
typedef __attribute__((ext_vector_type(8))) short bfx8;
typedef __attribute__((ext_vector_type(4))) float fx4;

__device__ __forceinline__ ushort f2bf(float f) {  // RNE
    uint u = __float_as_uint(f);
    u += 0x7fff + ((u >> 16) & 1);
    return (ushort)(u >> 16);
}

__device__ __forceinline__ uint cvtpk(float lo, float hi) {  // 2xf32 -> packed bf16
    uint r;
    asm("v_cvt_pk_bf16_f32 %0, %1, %2" : "=v"(r) : "v"(lo), "v"(hi));
    return r;
}

// ---------------- degree count (deg arrays memset to 0 host-side) ----------
__global__ __launch_bounds__(256) void k_count(const int* __restrict__ src,
                                               const int* __restrict__ dst, int E,
                                               int* __restrict__ dego,
                                               int* __restrict__ degi) {
    int e = blockIdx.x * 256 + threadIdx.x;
    if (e < E) {
        atomicAdd(&dego[src[e]], 1);
        atomicAdd(&degi[dst[e]], 1);
    }
}

// ---------------- CSR build (scan by dst; degi = real in-edges) -------------
// shfl-based block scan: 6 shuffle steps in-wave (no barriers) + 16-partial
// LDS scan by wave 0 + offset add. 2 barriers vs Hillis-Steele's 20.
__device__ __forceinline__ int block_scan_inc(int v, int* wsum) {
    int lane = threadIdx.x & 63, wid = threadIdx.x >> 6;
#pragma unroll
    for (int o = 1; o < 64; o <<= 1) {
        int u = __shfl_up(v, o);
        if (lane >= o) v += u;
    }
    if (lane == 63) wsum[wid] = v;
    __syncthreads();
    if (wid == 0) {
        int s = (lane < 16) ? wsum[lane] : 0;
#pragma unroll
        for (int o = 1; o < 16; o <<= 1) {
            int u = __shfl_up(s, o);
            if (lane >= o) s += u;
        }
        if (lane < 16) wsum[lane] = s;
    }
    __syncthreads();
    if (wid > 0) v += wsum[wid - 1];
    return v;
}

// scan1 fused with norm computation
__global__ __launch_bounds__(SCAN_BLK) void k_scan1n(const int* __restrict__ degi,
                                                     const int* __restrict__ dego,
                                                     int* __restrict__ partials,
                                                     float* __restrict__ ns,
                                                     float* __restrict__ nd) {
    __shared__ int wsum[16];
    int i = blockIdx.x * SCAN_BLK + threadIdx.x;
    int v = (i < NN) ? degi[i] : 0;
    if (i < NN) {
        ns[i] = rsqrtf((float)(dego[i] + 1));  // +1 = self-loop
        nd[i] = rsqrtf((float)(v + 1));
    }
    int incl = block_scan_inc(v, wsum);
    if (threadIdx.x == SCAN_BLK - 1) partials[blockIdx.x] = incl;
}

// scan2 fused with the W -> fragment-order Wf permutation (block 0 scans,
// blocks 1..64 convert). Wf: frag (c16,kf) = cols c16*16..+15, k kf*32..+31;
// lane l owns col c16*16+(l&15), k kf*32+(l>>4)*8..+7, at Wf[((c16*8+kf)*64+l)*8].
// A wave's bfx8 B-load is 64 lanes x 16 B CONTIGUOUS (1 KB burst).
__global__ __launch_bounds__(256) void k_scan2cw(int* __restrict__ partials, int nb,
                                                 const float* __restrict__ W1,
                                                 const float* __restrict__ W2,
                                                 ushort* __restrict__ Wf1,
                                                 ushort* __restrict__ Wf2) {
    if (blockIdx.x == 0) {
        __shared__ int sm[128];
        int t = threadIdx.x;
        int v = (t < 128 && t < nb) ? partials[t] : 0;
        if (t < 128) sm[t] = v;
        __syncthreads();
        for (int o = 1; o < 128; o <<= 1) {
            int x = (t < 128 && t >= o) ? sm[t - o] : 0;
            __syncthreads();
            if (t < 128) sm[t] += x;
            __syncthreads();
        }
        if (t < nb) partials[t] = sm[t] - v;  // exclusive
    } else {
        int tid = (blockIdx.x - 1) * 256 + threadIdx.x;  // 0..16383
        int m = tid >> 13;
        int r = tid & 8191;
        int lane = r & 63;
        int kf = (r >> 6) & 7;
        int c16 = r >> 9;
        int n = c16 * 16 + (lane & 15);
        int kb = kf * 32 + (lane >> 4) * 8;
        const float* W = m ? W2 : W1;
        ushort* Wf = m ? Wf2 : Wf1;
        uint4 u;
        u.x = (uint)f2bf(W[(size_t)(kb + 0) * DD + n]) |
              ((uint)f2bf(W[(size_t)(kb + 1) * DD + n]) << 16);
        u.y = (uint)f2bf(W[(size_t)(kb + 2) * DD + n]) |
              ((uint)f2bf(W[(size_t)(kb + 3) * DD + n]) << 16);
        u.z = (uint)f2bf(W[(size_t)(kb + 4) * DD + n]) |
              ((uint)f2bf(W[(size_t)(kb + 5) * DD + n]) << 16);
        u.w = (uint)f2bf(W[(size_t)(kb + 6) * DD + n]) |
              ((uint)f2bf(W[(size_t)(kb + 7) * DD + n]) << 16);
        *(uint4*)&Wf[(size_t)r * 8] = u;
    }
}

__global__ __launch_bounds__(SCAN_BLK) void k_scan3(const int* __restrict__ degi,
                                                    const int* __restrict__ partials,
                                                    int* __restrict__ rowptr,
                                                    int* __restrict__ cursor) {
    __shared__ int wsum[16];
    int i = blockIdx.x * SCAN_BLK + threadIdx.x;
    int v = (i < NN) ? degi[i] : 0;
    int incl = block_scan_inc(v, wsum);
    int excl = partials[blockIdx.x] + incl - v;
    if (i <= NN) rowptr[i] = excl;   // rowptr[NN] = E
    if (i < NN) cursor[i] = excl;
}

__global__ __launch_bounds__(256) void k_fill(const int* __restrict__ src,
                                              const int* __restrict__ dst, int E,
                                              int* __restrict__ cursor,
                                              int* __restrict__ eidx) {
    int e = blockIdx.x * 256 + threadIdx.x;
    if (e < E) {
        int d = dst[e];
        int p = atomicAdd(&cursor[d], 1);
        eidx[p] = src[e];
    }
}

// ---------------- MFMA GEMM: H = A @ W (optionally row-scaled) -------------
// r12 structure (best measured) + B DOUBLE-BUFFER: tile 128x256, BK=64,
// 512 threads (8 waves 2x4), wave tile 64x64, 32 KB LDS A dbuf.
// NEW vs r15: ldB(ks+1) is issued at the TOP of the iteration (into the
// other bfr2 slot) so its ~300-cycle L2 latency hides under the 32 MFMAs,
// like the A-prefetch already does. Previously it was issued right before
// __syncthreads(), whose compiler-emitted vmcnt(0) drain exposed the full
// latency on the critical path 4x per block. VGPR headroom: 64 -> ~96,
// still within the launch_bounds(512,4) 128-reg cap.
template <bool FP32A>
__global__ __launch_bounds__(512, 4) void k_mfgemm(const void* __restrict__ Av,
                                                   const float* __restrict__ nrm,
                                                   const ushort* __restrict__ Wf,
                                                   ushort* __restrict__ H) {
    __shared__ uint4 atq[2][128 * 8];  // A tile bf16 [128r][8 chunks], dbuf, 32 KB
    int t = threadIdx.x;
    int brow = blockIdx.x * 128;
    int lane = t & 63, w = t >> 6;
    int wr = w >> 2, wc = w & 3;       // wave grid 2x4
    int lg = lane >> 4, lr = lane & 15;

    // ---- A staging setup ----
    int sr = t >> 3, sc = t & 7;       // reg-staging coords (FP32A)
    int rows_[2];
#pragma unroll
    for (int i = 0; i < 2; ++i) {
        int r = brow + sr + i * 64;
        rows_[i] = (r < NN) ? r : NN - 1;  // tail clamp (stores masked)
    }
    float4 svf[2][2];
    uint gofs[2];                      // gload_lds coords (!FP32A)
    if (!FP32A) {
#pragma unroll
        for (int i = 0; i < 2; ++i) {
            int slot = (w * 2 + i) * 64;
            int r = slot / 8 + lane / 8;
            int cs = (lane & 7) ^ (r & 7);
            int row = brow + r;
            if (row >= NN) row = NN - 1;
            gofs[i] = (uint)(((size_t)row * DD + cs * 8) * 2);
        }
    }

    auto ldA = [&](int ks) {  // FP32A: issue global loads early
        const float* X = (const float*)Av;
#pragma unroll
        for (int i = 0; i < 2; ++i) {
            const float4* p =
                (const float4*)(X + (size_t)rows_[i] * DD + ks * 64 + sc * 8);
            svf[i][0] = p[0];
            svf[i][1] = p[1];
        }
    };
    auto wrA = [&](int buf) {  // FP32A: convert + swizzled LDS write (late)
#pragma unroll
        for (int i = 0; i < 2; ++i) {
            int r = sr + i * 64;
            uint4 u;
            u.x = cvtpk(svf[i][0].x, svf[i][0].y);
            u.y = cvtpk(svf[i][0].z, svf[i][0].w);
            u.z = cvtpk(svf[i][1].x, svf[i][1].y);
            u.w = cvtpk(svf[i][1].z, svf[i][1].w);
            atq[buf][r * 8 + (sc ^ (r & 7))] = u;
        }
    };
    auto stage = [&](int buf, int ks) {  // !FP32A: async direct-to-LDS
#pragma unroll
        for (int i = 0; i < 2; ++i) {
            int slot = (w * 2 + i) * 64;
            const char* g = (const char*)Av + gofs[i] + ks * 128;
            __builtin_amdgcn_global_load_lds(
                (const __attribute__((address_space(1))) uint*)g,
                (__attribute__((address_space(3))) uint*)&atq[buf][slot], 16, 0, 0);
        }
    };

    // ---- B: fragment-order, coalesced 1 KB bursts, DOUBLE-BUFFERED ----
    bfx8 bfr2[2][2][4];  // [slot][kk][ni]; slot/kk/ni all compile-time (unrolled)
    auto ldB = [&](int ks, int slot) {
#pragma unroll
        for (int kk = 0; kk < 2; ++kk)
#pragma unroll
            for (int ni = 0; ni < 4; ++ni)
                bfr2[slot][kk][ni] = *(const bfx8*)&Wf[
                    (((size_t)(wc * 4 + ni) * 8 + (ks * 2 + kk)) * 64 + lane) * 8];
    };

    fx4 acc[4][4];
#pragma unroll
    for (int mi = 0; mi < 4; ++mi)
#pragma unroll
        for (int ni = 0; ni < 4; ++ni)
            acc[mi][ni] = (fx4){0.f, 0.f, 0.f, 0.f};

    if (FP32A) { ldA(0); wrA(0); } else stage(0, 0);
    ldB(0, 0);
    __syncthreads();

    int buf = 0;
#pragma unroll
    for (int ks = 0; ks < 4; ++ks) {
        if (ks < 3) {
            ldB(ks + 1, (ks + 1) & 1);   // prefetch B early: hides under MFMAs
            if (FP32A) ldA(ks + 1);      // issue early: hide under MFMA
            else stage(buf ^ 1, ks + 1); // async into other buffer
        }
#pragma unroll
        for (int kk = 0; kk < 2; ++kk) {
#pragma unroll
            for (int mi = 0; mi < 4; ++mi) {
                int r = wr * 64 + mi * 16 + lr;
                int c = kk * 4 + lg;
                bfx8 af = *(const bfx8*)&atq[buf][r * 8 + (c ^ (r & 7))];
#pragma unroll
                for (int ni = 0; ni < 4; ++ni)
                    acc[mi][ni] = __builtin_amdgcn_mfma_f32_16x16x32_bf16(
                        af, bfr2[ks & 1][kk][ni], acc[mi][ni], 0, 0, 0);
            }
        }
        if (ks < 3 && FP32A) wrA(buf ^ 1);  // write late, other buffer
        __syncthreads();
        buf ^= 1;
    }
    // K-loop ends with a barrier: staging reads complete, atq reusable.

    // ---- epilogue via LDS, two 64-row halves (coalesced 16B stores) ----
    float scl[4][4];
    if (FP32A) {
#pragma unroll
        for (int mi = 0; mi < 4; ++mi)
#pragma unroll
            for (int j = 0; j < 4; ++j) {
                int row = brow + wr * 64 + mi * 16 + lg * 4 + j;
                scl[mi][j] = nrm[row < NN ? row : NN - 1];
            }
    }
    ushort* hs = (ushort*)&atq[0][0];  // 64 rows x 256 ushorts = 32 KB
#pragma unroll
    for (int h = 0; h < 2; ++h) {
        if (wr == h) {
#pragma unroll
            for (int mi = 0; mi < 4; ++mi)
#pragma unroll
                for (int ni = 0; ni < 4; ++ni)
#pragma unroll
                    for (int j = 0; j < 4; ++j) {
                        int rl = mi * 16 + lg * 4 + j;   // 0..63 within half
                        int c = wc * 64 + ni * 16 + lr;
                        float v = acc[mi][ni][j];
                        if (FP32A) v *= scl[mi][j];
                        hs[rl * 256 + (((c >> 3) ^ (rl & 7)) << 3) + (c & 7)] =
                            f2bf(v);
                    }
        }
        __syncthreads();
        {
            int rl = t >> 3;               // 0..63
            int grow = brow + h * 64 + rl;
            if (grow < NN) {
                ushort* hp = H + (size_t)grow * DD;
#pragma unroll
                for (int i = 0; i < 4; ++i) {
                    int ch = (t & 7) + i * 8;
                    uint4 v = *(const uint4*)&hs[rl * 256 + ((ch ^ (rl & 7)) << 3)];
                    *(uint4*)(hp + ch * 8) = v;
                }
            }
        }
        __syncthreads();
    }
}

// ---------------- SpMM (bf16 gather, fp32 accum): one wave per dst node ----
__global__ __launch_bounds__(256) void k_spmm_bf(const ushort* __restrict__ T,
                                                 const int* __restrict__ rowptr,
                                                 const int* __restrict__ eidx,
                                                 const float* __restrict__ nd,
                                                 const float* __restrict__ ns,
                                                 const float* __restrict__ bias,
                                                 ushort* __restrict__ obf,
                                                 float* __restrict__ of,
                                                 int layer1) {
    int wid = threadIdx.x >> 6, lane = threadIdx.x & 63;
    int node = blockIdx.x * 4 + wid;
    if (node >= NN) return;
    int c = lane << 2;  // 4 bf16 per lane
    uint2 sv = *(const uint2*)(T + (size_t)node * DD + c);  // self-loop
    float p0[4], p1[4], p2[4], p3[4];
    p0[0] = __uint_as_float(sv.x << 16);
    p0[1] = __uint_as_float(sv.x & 0xffff0000u);
    p0[2] = __uint_as_float(sv.y << 16);
    p0[3] = __uint_as_float(sv.y & 0xffff0000u);
#pragma unroll
    for (int j = 0; j < 4; ++j) { p1[j] = 0.f; p2[j] = 0.f; p3[j] = 0.f; }
    int e = rowptr[node], end = rowptr[node + 1];
    for (; e + 3 < end; e += 4) {
        int s0 = eidx[e], s1 = eidx[e + 1], s2 = eidx[e + 2], s3 = eidx[e + 3];
        uint2 v0 = *(const uint2*)(T + (size_t)s0 * DD + c);
        uint2 v1 = *(const uint2*)(T + (size_t)s1 * DD + c);
        uint2 v2 = *(const uint2*)(T + (size_t)s2 * DD + c);
        uint2 v3 = *(const uint2*)(T + (size_t)s3 * DD + c);
        p0[0] += __uint_as_float(v0.x << 16);
        p0[1] += __uint_as_float(v0.x & 0xffff0000u);
        p0[2] += __uint_as_float(v0.y << 16);
        p0[3] += __uint_as_float(v0.y & 0xffff0000u);
        p1[0] += __uint_as_float(v1.x << 16);
        p1[1] += __uint_as_float(v1.x & 0xffff0000u);
        p1[2] += __uint_as_float(v1.y << 16);
        p1[3] += __uint_as_float(v1.y & 0xffff0000u);
        p2[0] += __uint_as_float(v2.x << 16);
        p2[1] += __uint_as_float(v2.x & 0xffff0000u);
        p2[2] += __uint_as_float(v2.y << 16);
        p2[3] += __uint_as_float(v2.y & 0xffff0000u);
        p3[0] += __uint_as_float(v3.x << 16);
        p3[1] += __uint_as_float(v3.x & 0xffff0000u);
        p3[2] += __uint_as_float(v3.y << 16);
        p3[3] += __uint_as_float(v3.y & 0xffff0000u);
    }
    for (; e < end; ++e) {
        int s0 = eidx[e];
        uint2 v0 = *(const uint2*)(T + (size_t)s0 * DD + c);
        p0[0] += __uint_as_float(v0.x << 16);
        p0[1] += __uint_as_float(v0.x & 0xffff0000u);
        p0[2] += __uint_as_float(v0.y << 16);
        p0[3] += __uint_as_float(v0.y & 0xffff0000u);
    }
#pragma unroll
    for (int j = 0; j < 4; ++j) p0[j] += (p1[j] + p2[j]) + p3[j];
    float n = nd[node];
    float4 bb = *(const float4*)(bias + c);
    float o0 = fmaf(p0[0], n, bb.x);
    float o1 = fmaf(p0[1], n, bb.y);
    float o2 = fmaf(p0[2], n, bb.z);
    float o3 = fmaf(p0[3], n, bb.w);
    if (layer1) {
        float s = ns[node];
        o0 = fmaxf(o0, 0.f) * s; o1 = fmaxf(o1, 0.f) * s;
        o2 = fmaxf(o2, 0.f) * s; o3 = fmaxf(o3, 0.f) * s;
        uint lo = (uint)f2bf(o0) | ((uint)f2bf(o1) << 16);
        uint hi = (uint)f2bf(o2) | ((uint)f2bf(o3) << 16);
        *(uint2*)(obf + (size_t)node * DD + c) = make_uint2(lo, hi);
    } else {
        fx4 o = {o0, o1, o2, o3};
        __builtin_nontemporal_store(o, (fx4*)(of + (size_t)node * DD + c));
    }
}

extern "C" void kernel_launch(void* const* d_in, const int* in_sizes, int n_in,
                              void* d_out, int out_size, void* d_ws, size_t ws_size,
                              hipStream_t stream) {
    const float* features = (const float*)d_in[0];
    const int* src = (const int*)d_in[1];
    const int* dst = (const int*)d_in[2];
    const float* W1 = (const float*)d_in[3];
    const float* b1 = (const float*)d_in[4];
    const float* W2 = (const float*)d_in[5];
    const float* b2 = (const float*)d_in[6];
    int E = in_sizes[1];
    float* out = (float*)d_out;

    size_t off = 0;
    auto alloc = [&](size_t nbytes) -> void* {
        void* p = (char*)d_ws + off;
        off += (nbytes + 255) & ~(size_t)255;
        return p;
    };
    int* dego = (int*)alloc((size_t)NN * 4);      // offset 0
    int* degi = (int*)alloc((size_t)NN * 4);      // offset 400128 (contiguous)
    float* norm_src = (float*)alloc((size_t)NN * 4);
    float* norm_dst = (float*)alloc((size_t)NN * 4);
    int* rowptr = (int*)alloc((size_t)(NN + 1) * 4);
    int* cursor = (int*)alloc((size_t)NN * 4);
    int* partials = (int*)alloc(128 * 4);
    int* eidx = (int*)alloc((size_t)E * 4);
    ushort* Wf1 = (ushort*)alloc((size_t)DD * DD * 2);
    ushort* Wf2 = (ushort*)alloc((size_t)DD * DD * 2);
    ushort* Xbf = (ushort*)alloc((size_t)NN * DD * 2);
    ushort* Hbf = (ushort*)alloc((size_t)NN * DD * 2);

    const int NB = (NN + SCAN_BLK - 1) / SCAN_BLK;  // 98

    hipMemsetAsync(dego, 0, (size_t)2 * 400128, stream);  // dego+degi adjacent
    k_count<<<(E + 255) / 256, 256, 0, stream>>>(src, dst, E, dego, degi);
    k_scan1n<<<NB, SCAN_BLK, 0, stream>>>(degi, dego, partials, norm_src, norm_dst);
    k_scan2cw<<<65, 256, 0, stream>>>(partials, NB, W1, W2, Wf1, Wf2);
    k_scan3<<<NB, SCAN_BLK, 0, stream>>>(degi, partials, rowptr, cursor);
    k_fill<<<(E + 255) / 256, 256, 0, stream>>>(src, dst, E, cursor, eidx);

    dim3 ggrid((NN + 127) / 128);  // 782, single column pass (BN=256)
    // layer 1: H1 = ns.(X @ W1)  (scale in epilogue)
    k_mfgemm<true><<<ggrid, 512, 0, stream>>>(features, norm_src, Wf1, Hbf);
    k_spmm_bf<<<(NN + 3) / 4, 256, 0, stream>>>(Hbf, rowptr, eidx, norm_dst,
                                                norm_src, b1, Xbf, out, 1);
    // layer 2
    k_mfgemm<false><<<ggrid, 512, 0, stream>>>(Xbf, nullptr, Wf2, Hbf);
    k_spmm_bf<<<(NN + 3) / 4, 256, 0, stream>>>(Hbf, rowptr, eidx, norm_dst,
                                                norm_src, b2, nullptr, out, 0);
}